// Round 3
// baseline (147.188 us; speedup 1.0000x reference)
//
#include <hip/hip_runtime.h>
#include <math.h>

#define BT    34   // sequence length
#define TPR   17   // threads per row (each thread owns tokens j and j+17)
#define RPB   15   // rows per block (15*17 = 255 active threads of 256)
#define BLOCK 256

typedef float v2f __attribute__((ext_vector_type(2)));
typedef float v4f __attribute__((ext_vector_type(4)));

// log2(e)/sqrt(3): folds the 1/sqrt(hd) scale AND the exp->exp2 conversion into q.
#define QSCALE 0.83294037332470f

#if __has_builtin(__builtin_amdgcn_exp2f)
#define EXP2(x) __builtin_amdgcn_exp2f(x)
#else
#define EXP2(x) exp2f(x)
#endif

__device__ __forceinline__ void ln6(const float* x, const float* g, const float* b, float* o) {
  float mu = (x[0]+x[1]+x[2]+x[3]+x[4]+x[5]) * (1.0f/6.0f);
  float v = 0.f;
  #pragma unroll
  for (int c = 0; c < 6; ++c) { float d = x[c]-mu; v += d*d; }
  float inv = rsqrtf(v * (1.0f/6.0f) + 1e-5f);
  #pragma unroll
  for (int c = 0; c < 6; ++c) o[c] = (x[c]-mu)*inv*g[c] + b[c];
}

__global__ __launch_bounds__(BLOCK, 4)
void addtrans_kernel(const int* __restrict__ idx,
                     const float* __restrict__ tok_emb,
                     const float* __restrict__ pos_params,
                     const float* __restrict__ z10_enc,
                     const float* __restrict__ special_enc,
                     const float* __restrict__ wq,
                     const float* __restrict__ wk,
                     const float* __restrict__ wv,
                     const float* __restrict__ wo,
                     const float* __restrict__ ln1_g, const float* __restrict__ ln1_b,
                     const float* __restrict__ ln2_g, const float* __restrict__ ln2_b,
                     const float* __restrict__ lnf_g, const float* __restrict__ lnf_b,
                     const float* __restrict__ ffn_w1, const float* __restrict__ ffn_b1,
                     const float* __restrict__ ffn_w2, const float* __restrict__ ffn_b2,
                     const float* __restrict__ head_w,
                     float* __restrict__ out, int B)
{
  // kv only: RPB*34*12 floats = 24480 B  (head-interleaved k,v pairs per token)
  __shared__ __align__(16) float s_kv[RPB*BT*12];
  __shared__ float s_te[42];
  __shared__ float s_pos[BT*3];
  __shared__ float s_wq[18], s_wk[18], s_wv[18], s_wo[36], s_hw[18];
  __shared__ float s_g1[6], s_b1[6], s_g2[6], s_b2[6], s_gf[6], s_bf[6];
  __shared__ float s_w1[12], s_w2[12], s_fb1[2], s_fb2[6];

  const int tid = threadIdx.x;

  // ---- stage params / build pos table (once per block, trivial cost) ----
  if (tid < 42) s_te[tid] = tok_emb[tid];
  if (tid < 18) { s_wq[tid]=wq[tid]; s_wk[tid]=wk[tid]; s_wv[tid]=wv[tid]; s_hw[tid]=head_w[tid]; }
  if (tid < 36) s_wo[tid] = wo[tid];
  if (tid < 12) { s_w1[tid]=ffn_w1[tid]; s_w2[tid]=ffn_w2[tid]; }
  if (tid < 6)  { s_g1[tid]=ln1_g[tid]; s_b1[tid]=ln1_b[tid];
                  s_g2[tid]=ln2_g[tid]; s_b2[tid]=ln2_b[tid];
                  s_gf[tid]=lnf_g[tid]; s_bf[tid]=lnf_b[tid];
                  s_fb2[tid]=ffn_b2[tid]; }
  if (tid < 2)  s_fb1[tid] = ffn_b1[tid];
  if (tid < BT) {
    int p = tid, f;
    if (p < 10) f = p;
    else if (p == 10) f = 11;
    else if (p < 21) f = p - 11;
    else if (p == 21) f = 12;
    else if (p < 33) { int z = p - 22; f = (z < 10) ? z : 10; }
    else f = 13;
    float e0, e1, e2;
    if (f < 10) {
      float amp = pos_params[0], ph = pos_params[1], sl = pos_params[2], of = pos_params[3];
      float ang = 0.62831853071795864769f * (float)f + ph;  // 2*pi*f/10 + phase
      e0 = amp * cosf(ang); e1 = amp * sinf(ang); e2 = sl * (float)f + of;
    } else if (f == 10) { e0 = z10_enc[0]; e1 = z10_enc[1]; e2 = z10_enc[2]; }
    else { int u = f - 11; e0 = special_enc[u*3]; e1 = special_enc[u*3+1]; e2 = special_enc[u*3+2]; }
    s_pos[tid*3+0] = e0; s_pos[tid*3+1] = e1; s_pos[tid*3+2] = e2;
  }
  __syncthreads();

  const int row = tid / TPR;           // 0..15 (15 => inactive)
  const int j   = tid - row * TPR;     // 0..16
  const int b   = blockIdx.x * RPB + row;
  const bool active = (row < RPB) && (b < B);

  v2f   qp[2][3];                      // packed (head0, head1) per dim, scaled by QSCALE
  float xr[2][6];

  // ---- embed + ln1 + qkv for both owned tokens; publish interleaved k,v to LDS ----
  if (active) {
    const int base = b * BT;
    #pragma unroll
    for (int s = 0; s < 2; ++s) {
      const int t = j + s * TPR;
      const int vid = idx[base + t];
      float x6[6];
      x6[0] = s_te[vid*3+0]; x6[1] = s_te[vid*3+1]; x6[2] = s_te[vid*3+2];
      x6[3] = s_pos[t*3+0];  x6[4] = s_pos[t*3+1];  x6[5] = s_pos[t*3+2];
      float h[6];
      ln6(x6, s_g1, s_b1, h);
      float q6[6], k6[6], v6[6];
      #pragma unroll
      for (int c = 0; c < 6; ++c) {
        q6[c] = h[3]*s_wq[c] + h[4]*s_wq[6+c] + h[5]*s_wq[12+c];
        k6[c] = h[3]*s_wk[c] + h[4]*s_wk[6+c] + h[5]*s_wk[12+c];
        v6[c] = h[0]*s_wv[c] + h[1]*s_wv[6+c] + h[2]*s_wv[12+c];
        xr[s][c] = x6[c];
      }
      qp[s][0] = (v2f){q6[0]*QSCALE, q6[3]*QSCALE};
      qp[s][1] = (v2f){q6[1]*QSCALE, q6[4]*QSCALE};
      qp[s][2] = (v2f){q6[2]*QSCALE, q6[5]*QSCALE};
      v4f* kvp = (v4f*)&s_kv[(row*BT + t)*12];
      kvp[0] = (v4f){k6[0], k6[3], k6[1], k6[4]};   // k dim0/dim1 pairs
      kvp[1] = (v4f){k6[2], k6[5], v6[0], v6[3]};   // k dim2, v dim0
      kvp[2] = (v4f){v6[1], v6[4], v6[2], v6[5]};   // v dim1/dim2
    }
  }
  __syncthreads();

  // ---- causal attention, packed over the 2 heads, exp2 domain ----
  v2f l0 = (v2f){0.f,0.f}, l1 = (v2f){0.f,0.f};
  v2f o0[3] = {(v2f){0.f,0.f},(v2f){0.f,0.f},(v2f){0.f,0.f}};
  v2f o1[3] = {(v2f){0.f,0.f},(v2f){0.f,0.f},(v2f){0.f,0.f}};
  if (active) {
    const v4f* kvb = (const v4f*)&s_kv[row * (BT*12)];
    #pragma unroll 4
    for (int k = 0; k < TPR; ++k) {      // serves token j (masked) and j+17 (always <=)
      v4f A = kvb[k*3+0], Bv = kvb[k*3+1], C = kvb[k*3+2];
      v2f kA = (v2f){A.x, A.y}, kB = (v2f){A.z, A.w}, kC = (v2f){Bv.x, Bv.y};
      v2f vA = (v2f){Bv.z, Bv.w}, vB = (v2f){C.x, C.y}, vC = (v2f){C.z, C.w};
      v2f s0 = qp[0][0]*kA + qp[0][1]*kB + qp[0][2]*kC;
      const float mf = (k <= j) ? 1.f : 0.f;
      v2f p0 = (v2f){EXP2(s0.x), EXP2(s0.y)};
      p0 *= mf;
      l0 += p0; o0[0] += p0*vA; o0[1] += p0*vB; o0[2] += p0*vC;
      v2f s1 = qp[1][0]*kA + qp[1][1]*kB + qp[1][2]*kC;
      v2f p1 = (v2f){EXP2(s1.x), EXP2(s1.y)};
      l1 += p1; o1[0] += p1*vA; o1[1] += p1*vB; o1[2] += p1*vC;
    }
    #pragma unroll 4
    for (int k = TPR; k < BT; ++k) {     // serves only token j+17 (masked)
      v4f A = kvb[k*3+0], Bv = kvb[k*3+1], C = kvb[k*3+2];
      v2f kA = (v2f){A.x, A.y}, kB = (v2f){A.z, A.w}, kC = (v2f){Bv.x, Bv.y};
      v2f vA = (v2f){Bv.z, Bv.w}, vB = (v2f){C.x, C.y}, vC = (v2f){C.z, C.w};
      v2f s1 = qp[1][0]*kA + qp[1][1]*kB + qp[1][2]*kC;
      const float mf = (k <= j + TPR) ? 1.f : 0.f;
      v2f p1 = (v2f){EXP2(s1.x), EXP2(s1.y)};
      p1 *= mf;
      l1 += p1; o1[0] += p1*vA; o1[1] += p1*vB; o1[2] += p1*vC;
    }
  }

  // ---- epilogue: o/l, wo, residual, ln2, FFN(exact gelu), lnf, head, direct store ----
  if (active) {
    #pragma unroll
    for (int s = 0; s < 2; ++s) {
      const int t = j + s * TPR;
      const v2f  lv = s ? l1 : l0;
      const v2f* ov = s ? o1 : o0;
      const float ia = __builtin_amdgcn_rcpf(lv.x);
      const float ib = __builtin_amdgcn_rcpf(lv.y);
      float a6[6] = { ov[0].x*ia, ov[1].x*ia, ov[2].x*ia,
                      ov[0].y*ib, ov[1].y*ib, ov[2].y*ib };
      float xn[6];
      #pragma unroll
      for (int c = 0; c < 6; ++c) {
        xn[c] = xr[s][c]
              + a6[0]*s_wo[c]    + a6[1]*s_wo[6+c]  + a6[2]*s_wo[12+c]
              + a6[3]*s_wo[18+c] + a6[4]*s_wo[24+c] + a6[5]*s_wo[30+c];
      }
      float h2[6];
      ln6(xn, s_g2, s_b2, h2);
      float a0 = s_fb1[0], a1 = s_fb1[1];
      #pragma unroll
      for (int d = 0; d < 6; ++d) { a0 += h2[d]*s_w1[d*2]; a1 += h2[d]*s_w1[d*2+1]; }
      const float g0 = 0.5f*a0*(1.0f + erff(a0*0.70710678118654752440f));
      const float g1 = 0.5f*a1*(1.0f + erff(a1*0.70710678118654752440f));
      #pragma unroll
      for (int c = 0; c < 6; ++c) xn[c] += g0*s_w2[c] + g1*s_w2[6+c] + s_fb2[c];
      float xf[6];
      ln6(xn, s_gf, s_bf, xf);
      float y0 = 0.f, y1 = 0.f, y2 = 0.f;
      #pragma unroll
      for (int c = 0; c < 6; ++c) {
        y0 += xf[c]*s_hw[c*3+0]; y1 += xf[c]*s_hw[c*3+1]; y2 += xf[c]*s_hw[c*3+2];
      }
      float lg[14];
      #pragma unroll
      for (int j2 = 0; j2 < 14; ++j2)
        lg[j2] = y0*s_te[j2*3+0] + y1*s_te[j2*3+1] + y2*s_te[j2*3+2];
      // 14 floats contiguous per token, 8B-aligned -> 7 dwordx2 stores
      v2f* op2 = (v2f*)(out + ((size_t)b * BT + t) * 14);
      #pragma unroll
      for (int u = 0; u < 7; ++u)
        op2[u] = (v2f){lg[2*u], lg[2*u+1]};
    }
  }
}

extern "C" void kernel_launch(void* const* d_in, const int* in_sizes, int n_in,
                              void* d_out, int out_size, void* d_ws, size_t ws_size,
                              hipStream_t stream) {
  const int B = in_sizes[0] / BT;                 // 32768
  const int grid = (B + RPB - 1) / RPB;           // 2185
  addtrans_kernel<<<grid, BLOCK, 0, stream>>>(
      (const int*)d_in[0],   (const float*)d_in[1], (const float*)d_in[2],
      (const float*)d_in[3], (const float*)d_in[4], (const float*)d_in[5],
      (const float*)d_in[6], (const float*)d_in[7], (const float*)d_in[8],
      (const float*)d_in[9], (const float*)d_in[10], (const float*)d_in[11],
      (const float*)d_in[12], (const float*)d_in[13], (const float*)d_in[14],
      (const float*)d_in[15], (const float*)d_in[16], (const float*)d_in[17],
      (const float*)d_in[18], (const float*)d_in[19],
      (float*)d_out, B);
}

// Round 4
// 139.741 us; speedup vs baseline: 1.0533x; 1.0533x over previous
//
#include <hip/hip_runtime.h>
#include <math.h>

#define BT    34   // sequence length
#define TPR   17   // threads per row (each thread owns tokens j and j+17)
#define RPB   15   // rows per block (15*17 = 255 active threads of 256)
#define BLOCK 256

typedef float v2f __attribute__((ext_vector_type(2)));
typedef float v4f __attribute__((ext_vector_type(4)));

// log2(e)/sqrt(3): folds the 1/sqrt(hd) scale AND the exp->exp2 conversion into q.
#define QSCALE 0.83294037332470f

#if __has_builtin(__builtin_amdgcn_exp2f)
#define EXP2(x) __builtin_amdgcn_exp2f(x)
#else
#define EXP2(x) exp2f(x)
#endif

__device__ __forceinline__ void ln6(const float* x, const float* g, const float* b, float* o) {
  float mu = (x[0]+x[1]+x[2]+x[3]+x[4]+x[5]) * (1.0f/6.0f);
  float v = 0.f;
  #pragma unroll
  for (int c = 0; c < 6; ++c) { float d = x[c]-mu; v += d*d; }
  float inv = rsqrtf(v * (1.0f/6.0f) + 1e-5f);
  #pragma unroll
  for (int c = 0; c < 6; ++c) o[c] = (x[c]-mu)*inv*g[c] + b[c];
}

__global__ __launch_bounds__(BLOCK, 4)
void addtrans_kernel(const int* __restrict__ idx,
                     const float* __restrict__ tok_emb,
                     const float* __restrict__ pos_params,
                     const float* __restrict__ z10_enc,
                     const float* __restrict__ special_enc,
                     const float* __restrict__ wq,
                     const float* __restrict__ wk,
                     const float* __restrict__ wv,
                     const float* __restrict__ wo,
                     const float* __restrict__ ln1_g, const float* __restrict__ ln1_b,
                     const float* __restrict__ ln2_g, const float* __restrict__ ln2_b,
                     const float* __restrict__ lnf_g, const float* __restrict__ lnf_b,
                     const float* __restrict__ ffn_w1, const float* __restrict__ ffn_b1,
                     const float* __restrict__ ffn_w2, const float* __restrict__ ffn_b2,
                     const float* __restrict__ head_w,
                     float* __restrict__ out, int B)
{
  // kv phase uses first RPB*34*12 = 6120 floats (interleaved); logits phase RPB*34*14 = 7140
  __shared__ __align__(16) float s_mem[RPB*BT*14];
  __shared__ float s_te[42];
  __shared__ float s_pos[BT*3];
  __shared__ float s_wq[18], s_wk[18], s_wv[18], s_wo[36], s_hw[18];
  __shared__ float s_g1[6], s_b1[6], s_g2[6], s_b2[6], s_gf[6], s_bf[6];
  __shared__ float s_w1[12], s_w2[12], s_fb1[2], s_fb2[6];

  const int tid = threadIdx.x;

  // ---- stage params / build pos table (once per block, trivial cost) ----
  if (tid < 42) s_te[tid] = tok_emb[tid];
  if (tid < 18) { s_wq[tid]=wq[tid]; s_wk[tid]=wk[tid]; s_wv[tid]=wv[tid]; s_hw[tid]=head_w[tid]; }
  if (tid < 36) s_wo[tid] = wo[tid];
  if (tid < 12) { s_w1[tid]=ffn_w1[tid]; s_w2[tid]=ffn_w2[tid]; }
  if (tid < 6)  { s_g1[tid]=ln1_g[tid]; s_b1[tid]=ln1_b[tid];
                  s_g2[tid]=ln2_g[tid]; s_b2[tid]=ln2_b[tid];
                  s_gf[tid]=lnf_g[tid]; s_bf[tid]=lnf_b[tid];
                  s_fb2[tid]=ffn_b2[tid]; }
  if (tid < 2)  s_fb1[tid] = ffn_b1[tid];
  if (tid < BT) {
    int p = tid, f;
    if (p < 10) f = p;
    else if (p == 10) f = 11;
    else if (p < 21) f = p - 11;
    else if (p == 21) f = 12;
    else if (p < 33) { int z = p - 22; f = (z < 10) ? z : 10; }
    else f = 13;
    float e0, e1, e2;
    if (f < 10) {
      float amp = pos_params[0], ph = pos_params[1], sl = pos_params[2], of = pos_params[3];
      float ang = 0.62831853071795864769f * (float)f + ph;  // 2*pi*f/10 + phase
      e0 = amp * cosf(ang); e1 = amp * sinf(ang); e2 = sl * (float)f + of;
    } else if (f == 10) { e0 = z10_enc[0]; e1 = z10_enc[1]; e2 = z10_enc[2]; }
    else { int u = f - 11; e0 = special_enc[u*3]; e1 = special_enc[u*3+1]; e2 = special_enc[u*3+2]; }
    s_pos[tid*3+0] = e0; s_pos[tid*3+1] = e1; s_pos[tid*3+2] = e2;
  }
  __syncthreads();

  const int row = tid / TPR;           // 0..15 (15 => inactive)
  const int j   = tid - row * TPR;     // 0..16
  const int b   = blockIdx.x * RPB + row;
  const bool active = (row < RPB) && (b < B);

  v2f   qp[2][3];                      // packed (head0, head1) per dim, scaled by QSCALE
  float xr[2][6];

  // ---- embed + ln1 + qkv for both owned tokens; publish interleaved k,v to LDS ----
  if (active) {
    const int base = b * BT;
    #pragma unroll
    for (int s = 0; s < 2; ++s) {
      const int t = j + s * TPR;
      const int vid = idx[base + t];
      float x6[6];
      x6[0] = s_te[vid*3+0]; x6[1] = s_te[vid*3+1]; x6[2] = s_te[vid*3+2];
      x6[3] = s_pos[t*3+0];  x6[4] = s_pos[t*3+1];  x6[5] = s_pos[t*3+2];
      float h[6];
      ln6(x6, s_g1, s_b1, h);
      float q6[6], k6[6], v6[6];
      #pragma unroll
      for (int c = 0; c < 6; ++c) {
        q6[c] = h[3]*s_wq[c] + h[4]*s_wq[6+c] + h[5]*s_wq[12+c];
        k6[c] = h[3]*s_wk[c] + h[4]*s_wk[6+c] + h[5]*s_wk[12+c];
        v6[c] = h[0]*s_wv[c] + h[1]*s_wv[6+c] + h[2]*s_wv[12+c];
        xr[s][c] = x6[c];
      }
      qp[s][0] = (v2f){q6[0]*QSCALE, q6[3]*QSCALE};
      qp[s][1] = (v2f){q6[1]*QSCALE, q6[4]*QSCALE};
      qp[s][2] = (v2f){q6[2]*QSCALE, q6[5]*QSCALE};
      v4f* kvp = (v4f*)&s_mem[(row*BT + t)*12];
      kvp[0] = (v4f){k6[0], k6[3], k6[1], k6[4]};   // k dim0/dim1 head-pairs
      kvp[1] = (v4f){k6[2], k6[5], v6[0], v6[3]};   // k dim2, v dim0
      kvp[2] = (v4f){v6[1], v6[4], v6[2], v6[5]};   // v dim1/dim2
    }
  }
  __syncthreads();

  // ---- causal attention, packed over the 2 heads, exp2 domain ----
  v2f l0 = (v2f){0.f,0.f}, l1 = (v2f){0.f,0.f};
  v2f o0[3] = {(v2f){0.f,0.f},(v2f){0.f,0.f},(v2f){0.f,0.f}};
  v2f o1[3] = {(v2f){0.f,0.f},(v2f){0.f,0.f},(v2f){0.f,0.f}};
  if (active) {
    const v4f* kvb = (const v4f*)&s_mem[row * (BT*12)];
    #pragma unroll 4
    for (int k = 0; k < TPR; ++k) {      // serves token j (masked) and j+17 (always <=)
      v4f A = kvb[k*3+0], Bv = kvb[k*3+1], C = kvb[k*3+2];
      v2f kA = (v2f){A.x, A.y}, kB = (v2f){A.z, A.w}, kC = (v2f){Bv.x, Bv.y};
      v2f vA = (v2f){Bv.z, Bv.w}, vB = (v2f){C.x, C.y}, vC = (v2f){C.z, C.w};
      v2f s0 = qp[0][0]*kA + qp[0][1]*kB + qp[0][2]*kC;
      const float mf = (k <= j) ? 1.f : 0.f;
      v2f p0 = (v2f){EXP2(s0.x), EXP2(s0.y)};
      p0 *= mf;
      l0 += p0; o0[0] += p0*vA; o0[1] += p0*vB; o0[2] += p0*vC;
      v2f s1 = qp[1][0]*kA + qp[1][1]*kB + qp[1][2]*kC;
      v2f p1 = (v2f){EXP2(s1.x), EXP2(s1.y)};
      l1 += p1; o1[0] += p1*vA; o1[1] += p1*vB; o1[2] += p1*vC;
    }
    #pragma unroll 4
    for (int k = TPR; k < BT; ++k) {     // serves only token j+17 (masked)
      v4f A = kvb[k*3+0], Bv = kvb[k*3+1], C = kvb[k*3+2];
      v2f kA = (v2f){A.x, A.y}, kB = (v2f){A.z, A.w}, kC = (v2f){Bv.x, Bv.y};
      v2f vA = (v2f){Bv.z, Bv.w}, vB = (v2f){C.x, C.y}, vC = (v2f){C.z, C.w};
      v2f s1 = qp[1][0]*kA + qp[1][1]*kB + qp[1][2]*kC;
      const float mf = (k <= j + TPR) ? 1.f : 0.f;
      v2f p1 = (v2f){EXP2(s1.x), EXP2(s1.y)};
      p1 *= mf;
      l1 += p1; o1[0] += p1*vA; o1[1] += p1*vB; o1[2] += p1*vC;
    }
  }
  __syncthreads();   // all kv reads done; s_mem is free for logits

  // ---- epilogue: o/l, wo, residual, ln2, FFN(exact gelu), lnf, head -> LDS ----
  if (active) {
    #pragma unroll
    for (int s = 0; s < 2; ++s) {
      const int t = j + s * TPR;
      const v2f  lv = s ? l1 : l0;
      const v2f* ov = s ? o1 : o0;
      const float ia = __builtin_amdgcn_rcpf(lv.x);
      const float ib = __builtin_amdgcn_rcpf(lv.y);
      float a6[6] = { ov[0].x*ia, ov[1].x*ia, ov[2].x*ia,
                      ov[0].y*ib, ov[1].y*ib, ov[2].y*ib };
      float xn[6];
      #pragma unroll
      for (int c = 0; c < 6; ++c) {
        xn[c] = xr[s][c]
              + a6[0]*s_wo[c]    + a6[1]*s_wo[6+c]  + a6[2]*s_wo[12+c]
              + a6[3]*s_wo[18+c] + a6[4]*s_wo[24+c] + a6[5]*s_wo[30+c];
      }
      float h2[6];
      ln6(xn, s_g2, s_b2, h2);
      float a0 = s_fb1[0], a1 = s_fb1[1];
      #pragma unroll
      for (int d = 0; d < 6; ++d) { a0 += h2[d]*s_w1[d*2]; a1 += h2[d]*s_w1[d*2+1]; }
      const float g0 = 0.5f*a0*(1.0f + erff(a0*0.70710678118654752440f));
      const float g1 = 0.5f*a1*(1.0f + erff(a1*0.70710678118654752440f));
      #pragma unroll
      for (int c = 0; c < 6; ++c) xn[c] += g0*s_w2[c] + g1*s_w2[6+c] + s_fb2[c];
      float xf[6];
      ln6(xn, s_gf, s_bf, xf);
      float y0 = 0.f, y1 = 0.f, y2 = 0.f;
      #pragma unroll
      for (int c = 0; c < 6; ++c) {
        y0 += xf[c]*s_hw[c*3+0]; y1 += xf[c]*s_hw[c*3+1]; y2 += xf[c]*s_hw[c*3+2];
      }
      // stage logits to LDS as v2f pairs (7 ds_write_b64)
      v2f* lp = (v2f*)&s_mem[(row*BT + t)*14];
      #pragma unroll
      for (int u = 0; u < 7; ++u) {
        const int c0 = 2*u, c1 = 2*u+1;
        lp[u] = (v2f){ y0*s_te[c0*3+0] + y1*s_te[c0*3+1] + y2*s_te[c0*3+2],
                       y0*s_te[c1*3+0] + y1*s_te[c1*3+1] + y2*s_te[c1*3+2] };
      }
    }
  }
  __syncthreads();

  // ---- coalesced nontemporal v4f store of the block's contiguous output ----
  {
    const int b0 = blockIdx.x * RPB;
    int nrows = B - b0; if (nrows > RPB) nrows = RPB;
    if (nrows > 0) {
      const int n4 = nrows * (BT*14/4);   // 476/4 = 119 vec4 per row
      v4f* dst = reinterpret_cast<v4f*>(out + (size_t)b0 * (BT*14));
      const v4f* src = reinterpret_cast<const v4f*>(s_mem);
      for (int i = tid; i < n4; i += BLOCK)
        __builtin_nontemporal_store(src[i], dst + i);
    }
  }
}

extern "C" void kernel_launch(void* const* d_in, const int* in_sizes, int n_in,
                              void* d_out, int out_size, void* d_ws, size_t ws_size,
                              hipStream_t stream) {
  const int B = in_sizes[0] / BT;                 // 32768
  const int grid = (B + RPB - 1) / RPB;           // 2185
  addtrans_kernel<<<grid, BLOCK, 0, stream>>>(
      (const int*)d_in[0],   (const float*)d_in[1], (const float*)d_in[2],
      (const float*)d_in[3], (const float*)d_in[4], (const float*)d_in[5],
      (const float*)d_in[6], (const float*)d_in[7], (const float*)d_in[8],
      (const float*)d_in[9], (const float*)d_in[10], (const float*)d_in[11],
      (const float*)d_in[12], (const float*)d_in[13], (const float*)d_in[14],
      (const float*)d_in[15], (const float*)d_in[16], (const float*)d_in[17],
      (const float*)d_in[18], (const float*)d_in[19],
      (float*)d_out, B);
}